// Round 4
// baseline (752.195 us; speedup 1.0000x reference)
//
#include <hip/hip_runtime.h>

// RGCN featureless, N=100000 nodes, S=50 rel, B=30 bases, OUT=16, E=20000.
// Index identity: k = r*N + dst; node' = k/50; rel' = k%50.
// Relation r's W slab = 3.84 MB -> fits one XCD's 4 MiB L2 (XCD affinity).
// Round-4 structure: counting-sort edges by src to replace 16M f32 atomic
// RMWs (TCC channel-bound, ~2/3 of round-3 time) with streamed 64B writes.
constexpr int S_REL = 50;
constexpr int B_BASES = 30;
constexpr int OUT_DIM = 16;
constexpr int NXCD = 8;
constexpr int EDGES_PER_BLOCK = 64;   // 256 threads, 4 lanes/edge

// ---------- sort-free fallback (round-3 path), used if ws too small ----------
__global__ __launch_bounds__(256) void relu_inplace_kernel(float4* __restrict__ p, int n4) {
    int i = blockIdx.x * blockDim.x + threadIdx.x;
    int stride = gridDim.x * blockDim.x;
    for (; i < n4; i += stride) {
        float4 v = p[i];
        v.x = fmaxf(v.x, 0.f); v.y = fmaxf(v.y, 0.f);
        v.z = fmaxf(v.z, 0.f); v.w = fmaxf(v.w, 0.f);
        p[i] = v;
    }
}

__global__ __launch_bounds__(256) void rgcn_edge_atomic_kernel(
    const int* __restrict__ src, const int* __restrict__ dst,
    const float* __restrict__ vals, const float* __restrict__ W,
    const float* __restrict__ Wcomp, float* __restrict__ out,
    int N, int E, int nEdges, int chunksPerXcd, int nChunks) {
    __shared__ float wc[S_REL * B_BASES];
    for (int i = threadIdx.x; i < S_REL * B_BASES; i += blockDim.x) wc[i] = Wcomp[i];
    __syncthreads();
    const int x = blockIdx.x % NXCD;
    const int j = blockIdx.x / NXCD;
    const int chunk = x * chunksPerXcd + j;
    if (chunk >= nChunks) return;
    const int edge = chunk * EDGES_PER_BLOCK + (threadIdx.x >> 2);
    const int o4 = (threadIdx.x & 3) * 4;
    if (edge >= nEdges) return;
    const int r = edge / E;
    const int d = dst[edge];
    const int s = src[edge];
    const float v = vals[edge];
    const int k = r * N + d;
    const int node = k / S_REL;
    const int rel = k - node * S_REL;
    const float* wp = W + (size_t)node * OUT_DIM + o4;
    const size_t bstride = (size_t)N * OUT_DIM;
    const float* wcr = wc + rel * B_BASES;
    float4 acc = make_float4(0.f, 0.f, 0.f, 0.f);
#pragma unroll
    for (int b = 0; b < B_BASES; ++b) {
        float4 w4 = *reinterpret_cast<const float4*>(wp + (size_t)b * bstride);
        float c = wcr[b];
        acc.x = fmaf(c, w4.x, acc.x); acc.y = fmaf(c, w4.y, acc.y);
        acc.z = fmaf(c, w4.z, acc.z); acc.w = fmaf(c, w4.w, acc.w);
    }
    float* op = out + (size_t)s * OUT_DIM + o4;
    atomicAdd(op + 0, v * acc.x); atomicAdd(op + 1, v * acc.y);
    atomicAdd(op + 2, v * acc.z); atomicAdd(op + 3, v * acc.w);
}

// ---------- round-4 pipeline ----------
__global__ __launch_bounds__(256) void hist_kernel(
    const int* __restrict__ src, unsigned* __restrict__ cnt, int nEdges) {
    int i = blockIdx.x * blockDim.x + threadIdx.x;
    int stride = gridDim.x * blockDim.x;
    for (; i < nEdges; i += stride) atomicAdd(&cnt[src[i]], 1u);
}

// Single-block exclusive scan over N counts -> offs (N+1) and cursor copy.
__global__ __launch_bounds__(1024) void scan_kernel(
    const unsigned* __restrict__ cnt, unsigned* __restrict__ offs,
    unsigned* __restrict__ cur, int N) {
    __shared__ unsigned sums[1024];
    const int t = threadIdx.x;
    const int per = (N + 1023) / 1024;
    const int lo = t * per;
    const int hi = (lo + per < N) ? lo + per : N;
    unsigned s = 0;
    for (int i = lo; i < hi; ++i) s += cnt[i];
    sums[t] = s;
    __syncthreads();
    for (int d = 1; d < 1024; d <<= 1) {
        unsigned v = (t >= d) ? sums[t - d] : 0u;
        __syncthreads();
        sums[t] += v;
        __syncthreads();
    }
    unsigned base = (t == 0) ? 0u : sums[t - 1];
    for (int i = lo; i < hi; ++i) {
        unsigned c = cnt[i];
        offs[i] = base;
        cur[i] = base;
        base += c;
    }
    if (t == 1023) offs[N] = sums[1023];
}

// Gather W (XCD-relation affinity), compute msg = val * (Wcomp . W-slab row),
// write the 64B message line into its sorted-by-src slot (no f32 atomics).
__global__ __launch_bounds__(256) void gather_kernel(
    const int* __restrict__ src, const int* __restrict__ dst,
    const float* __restrict__ vals, const float* __restrict__ W,
    const float* __restrict__ Wcomp, float* __restrict__ msgs,
    unsigned* __restrict__ cur,
    int N, int E, int nEdges, int chunksPerXcd, int nChunks) {
    __shared__ float wc[S_REL * B_BASES];
    for (int i = threadIdx.x; i < S_REL * B_BASES; i += blockDim.x) wc[i] = Wcomp[i];
    __syncthreads();

    const int x = blockIdx.x % NXCD;          // physical XCD (round-robin)
    const int j = blockIdx.x / NXCD;
    const int chunk = x * chunksPerXcd + j;   // contiguous edge range per XCD
    if (chunk >= nChunks) return;
    const int edge = chunk * EDGES_PER_BLOCK + (threadIdx.x >> 2);
    const int o4 = (threadIdx.x & 3) * 4;
    if (edge >= nEdges) return;

    const int r = edge / E;
    const int d = dst[edge];
    const int s = src[edge];
    const float v = vals[edge];
    const int k = r * N + d;
    const int node = k / S_REL;               // const divisor -> magic mul
    const int rel = k - node * S_REL;

    const float* wp = W + (size_t)node * OUT_DIM + o4;
    const size_t bstride = (size_t)N * OUT_DIM;
    const float* wcr = wc + rel * B_BASES;

    float4 acc = make_float4(0.f, 0.f, 0.f, 0.f);
#pragma unroll
    for (int b = 0; b < B_BASES; ++b) {
        float4 w4 = *reinterpret_cast<const float4*>(wp + (size_t)b * bstride);
        float c = wcr[b];
        acc.x = fmaf(c, w4.x, acc.x); acc.y = fmaf(c, w4.y, acc.y);
        acc.z = fmaf(c, w4.z, acc.z); acc.w = fmaf(c, w4.w, acc.w);
    }

    // one cursor fetch_add per edge, broadcast to the 4 lanes
    unsigned pos = 0;
    if ((threadIdx.x & 3) == 0) pos = atomicAdd(&cur[s], 1u);
    pos = __shfl(pos, 0, 4);

    float4* mp = reinterpret_cast<float4*>(msgs + (size_t)pos * OUT_DIM);
    mp[threadIdx.x & 3] = make_float4(v * acc.x, v * acc.y, v * acc.z, v * acc.w);
}

// One 4-lane group per node: sum its contiguous message segment, ReLU, store.
// Covers every node (deg-0 writes zeros) -> no zero-init or relu pass needed.
__global__ __launch_bounds__(256) void reduce_kernel(
    const float* __restrict__ msgs, const unsigned* __restrict__ offs,
    float* __restrict__ out, int N) {
    const int t = blockIdx.x * blockDim.x + threadIdx.x;
    const int n = t >> 2;
    const int q = t & 3;
    if (n >= N) return;
    const unsigned b = offs[n];
    const unsigned e = offs[n + 1];
    float4 acc = make_float4(0.f, 0.f, 0.f, 0.f);
    for (unsigned p = b; p < e; ++p) {
        float4 m = *reinterpret_cast<const float4*>(msgs + (size_t)p * OUT_DIM + q * 4);
        acc.x += m.x; acc.y += m.y; acc.z += m.z; acc.w += m.w;
    }
    float4* op = reinterpret_cast<float4*>(out + (size_t)n * OUT_DIM);
    op[q] = make_float4(fmaxf(acc.x, 0.f), fmaxf(acc.y, 0.f),
                        fmaxf(acc.z, 0.f), fmaxf(acc.w, 0.f));
}

extern "C" void kernel_launch(void* const* d_in, const int* in_sizes, int n_in,
                              void* d_out, int out_size, void* d_ws, size_t ws_size,
                              hipStream_t stream) {
    // setup_inputs order: features, src, dst, vals, W, W_comp
    const int* src = (const int*)d_in[1];
    const int* dst = (const int*)d_in[2];
    const float* vals = (const float*)d_in[3];
    const float* W = (const float*)d_in[4];
    const float* Wcomp = (const float*)d_in[5];
    float* out = (float*)d_out;

    const int N = in_sizes[0];
    const int nEdges = in_sizes[1];
    const int E = nEdges / S_REL;

    const int nChunks = (nEdges + EDGES_PER_BLOCK - 1) / EDGES_PER_BLOCK;
    const int chunksPerXcd = (nChunks + NXCD - 1) / NXCD;
    const int eblocks = chunksPerXcd * NXCD;

    // ws layout: msgs (nEdges*16 f32) | cnt (N u32) | offs (N+1 u32) | cur (N u32)
    const size_t msgsBytes = (size_t)nEdges * OUT_DIM * sizeof(float);
    const size_t needed = msgsBytes + (size_t)(3 * N + 1) * sizeof(unsigned);

    if (ws_size < needed) {
        // fallback: round-3 atomic path
        hipMemsetAsync(d_out, 0, (size_t)out_size * sizeof(float), stream);
        rgcn_edge_atomic_kernel<<<eblocks, 256, 0, stream>>>(
            src, dst, vals, W, Wcomp, out, N, E, nEdges, chunksPerXcd, nChunks);
        const int n4 = out_size / 4;
        int zb = (n4 + 255) / 256;
        relu_inplace_kernel<<<(zb < 2048 ? zb : 2048), 256, 0, stream>>>((float4*)out, n4);
        return;
    }

    float* msgs = (float*)d_ws;
    unsigned* cnt = (unsigned*)((char*)d_ws + msgsBytes);
    unsigned* offs = cnt + N;
    unsigned* cur = offs + N + 1;

    hipMemsetAsync(cnt, 0, (size_t)N * sizeof(unsigned), stream);

    int hb = (nEdges + 255) / 256;
    hist_kernel<<<(hb < 2048 ? hb : 2048), 256, 0, stream>>>(src, cnt, nEdges);

    scan_kernel<<<1, 1024, 0, stream>>>(cnt, offs, cur, N);

    gather_kernel<<<eblocks, 256, 0, stream>>>(src, dst, vals, W, Wcomp, msgs, cur,
                                               N, E, nEdges, chunksPerXcd, nChunks);

    const int rblocks = (N * 4 + 255) / 256;
    reduce_kernel<<<rblocks, 256, 0, stream>>>(msgs, offs, out, N);
}